// Round 11
// baseline (305.810 us; speedup 1.0000x reference)
//
#include <hip/hip_runtime.h>

typedef __bf16 bf16x4 __attribute__((ext_vector_type(4)));
typedef __bf16 bf16x8 __attribute__((ext_vector_type(8)));
typedef float floatx4 __attribute__((ext_vector_type(4)));

#define MFMA16(a, b, c) __builtin_amdgcn_mfma_f32_16x16x32_bf16((a), (b), (c), 0, 0, 0)

constexpr int D_MODEL = 1024;
constexpr int SEQ = 2048;
constexpr int HEAD_DIM = 64;
constexpr int M_TOK = 2 * SEQ;   // 4096 tokens (B=2)
constexpr int N_HEADS = 16;
constexpr float ROPE_C = 0.20762050593048596f;   // log2(10000)/64

// 8 fp32 -> bf16x8 in-register convert (validated r4/r5 numerics)
__device__ __forceinline__ bf16x8 cvt8(const float* f)
{
    const floatx4 lo = *(const floatx4*)f;
    const floatx4 hi = *(const floatx4*)(f + 4);
    bf16x8 v;
    v[0] = (__bf16)lo[0]; v[1] = (__bf16)lo[1]; v[2] = (__bf16)lo[2]; v[3] = (__bf16)lo[3];
    v[4] = (__bf16)hi[0]; v[5] = (__bf16)hi[1]; v[6] = (__bf16)hi[2]; v[7] = (__bf16)hi[3];
    return v;
}

// ---------------------------------------------------------------------------
// Tiled GEMM with FUSED fp32->bf16 conversion in the staging path (replaces
// the convert_all prepass + Xb/Wb round-trip). 128x128 tile, 4 waves, BK=32,
// unpadded 64-B LDS rows, 16 named floatx4 accumulators (r8 spill fix).
// MODE 0: A = x (fp32); B selected per 1024-col region from {Wq,Wk,Wv} (fp32);
//         fused QKV epilogue (+RoPE for Q,K; V transposed per head).
// MODE 1: A = attn output (bf16); B = Wo (fp32); plain fp32 C output.
// ---------------------------------------------------------------------------
template<int MODE>
__global__ __launch_bounds__(256, 2) void gemm_tiled(
    const void* __restrict__ A, const float* __restrict__ B0,
    const float* __restrict__ B1, const float* __restrict__ B2,
    __bf16* __restrict__ Qb, __bf16* __restrict__ Kb, __bf16* __restrict__ Vt,
    float* __restrict__ Cf, const int* __restrict__ tokpos)
{
    __shared__ __bf16 As[128 * 32];
    __shared__ __bf16 Bs[128 * 32];
    const int tid  = threadIdx.x;
    const int wave = tid >> 6, lane = tid & 63;
    const int quad = lane >> 4, l16 = lane & 15;
    const int m0 = blockIdx.x * 128, n0 = blockIdx.y * 128;
    const int wm = (wave >> 1) * 64, wn = (wave & 1) * 64;

    floatx4 c00 = {}, c01 = {}, c02 = {}, c03 = {};
    floatx4 c10 = {}, c11 = {}, c12 = {}, c13 = {};
    floatx4 c20 = {}, c21 = {}, c22 = {}, c23 = {};
    floatx4 c30 = {}, c31 = {}, c32 = {}, c33 = {};

    const int sm = tid >> 2;              // staging row
    const int sk = (tid & 3) * 8;         // staging col (elements)

    const float*  gAf = (const float*)A  + (size_t)(m0 + sm) * D_MODEL + sk;
    const __bf16* gAb = (const __bf16*)A + (size_t)(m0 + sm) * D_MODEL + sk;

    const float* Bp; int nb;
    if (MODE == 0) {
        Bp = (n0 < 1024) ? B0 : (n0 < 2048) ? B1 : B2;
        nb = n0 & 1023;
    } else { Bp = B0; nb = n0; }
    const float* gB = Bp + (size_t)(nb + sm) * D_MODEL + sk;

    for (int k0 = 0; k0 < D_MODEL; k0 += 32) {
        __syncthreads();
        if (MODE == 0) {
            *(bf16x8*)&As[sm * 32 + sk]        = cvt8(gAf + k0);
            *(bf16x8*)&As[(sm + 64) * 32 + sk] = cvt8(gAf + (size_t)64 * D_MODEL + k0);
        } else {
            *(bf16x8*)&As[sm * 32 + sk]        = *(const bf16x8*)(gAb + k0);
            *(bf16x8*)&As[(sm + 64) * 32 + sk] = *(const bf16x8*)(gAb + (size_t)64 * D_MODEL + k0);
        }
        *(bf16x8*)&Bs[sm * 32 + sk]        = cvt8(gB + k0);
        *(bf16x8*)&Bs[(sm + 64) * 32 + sk] = cvt8(gB + (size_t)64 * D_MODEL + k0);
        __syncthreads();

        const bf16x8 a0 = *(const bf16x8*)&As[(wm      + l16) * 32 + quad * 8];
        const bf16x8 a1 = *(const bf16x8*)&As[(wm + 16 + l16) * 32 + quad * 8];
        const bf16x8 a2 = *(const bf16x8*)&As[(wm + 32 + l16) * 32 + quad * 8];
        const bf16x8 a3 = *(const bf16x8*)&As[(wm + 48 + l16) * 32 + quad * 8];
        const bf16x8 b0 = *(const bf16x8*)&Bs[(wn      + l16) * 32 + quad * 8];
        const bf16x8 b1 = *(const bf16x8*)&Bs[(wn + 16 + l16) * 32 + quad * 8];
        const bf16x8 b2 = *(const bf16x8*)&Bs[(wn + 32 + l16) * 32 + quad * 8];
        const bf16x8 b3 = *(const bf16x8*)&Bs[(wn + 48 + l16) * 32 + quad * 8];

        c00 = MFMA16(a0, b0, c00); c01 = MFMA16(a0, b1, c01);
        c02 = MFMA16(a0, b2, c02); c03 = MFMA16(a0, b3, c03);
        c10 = MFMA16(a1, b0, c10); c11 = MFMA16(a1, b1, c11);
        c12 = MFMA16(a1, b2, c12); c13 = MFMA16(a1, b3, c13);
        c20 = MFMA16(a2, b0, c20); c21 = MFMA16(a2, b1, c21);
        c22 = MFMA16(a2, b2, c22); c23 = MFMA16(a2, b3, c23);
        c30 = MFMA16(a3, b0, c30); c31 = MFMA16(a3, b1, c31);
        c32 = MFMA16(a3, b2, c32); c33 = MFMA16(a3, b3, c33);
    }

#define EPI(I, J, CV) do {                                                     \
        const int n  = n0 + wn + (J) * 16 + l16;                               \
        const int t0 = m0 + wm + (I) * 16 + quad * 4;                          \
        if (MODE == 1) {                                                       \
            Cf[(size_t)(t0 + 0) * D_MODEL + n] = (CV)[0];                      \
            Cf[(size_t)(t0 + 1) * D_MODEL + n] = (CV)[1];                      \
            Cf[(size_t)(t0 + 2) * D_MODEL + n] = (CV)[2];                      \
            Cf[(size_t)(t0 + 3) * D_MODEL + n] = (CV)[3];                      \
        } else {                                                               \
            const int region = n >> 10, col = n & 1023;                        \
            if (region == 2) {                                                 \
                bf16x4 v;                                                      \
                v[0] = (__bf16)(CV)[0]; v[1] = (__bf16)(CV)[1];                \
                v[2] = (__bf16)(CV)[2]; v[3] = (__bf16)(CV)[3];                \
                const size_t vidx =                                            \
                    ((size_t)(t0 >> 11) * 1024 + col) * SEQ + (t0 & (SEQ - 1));\
                *(bf16x4*)(Vt + vidx) = v;                                     \
            } else {                                                           \
                const int d = col & (HEAD_DIM - 1);                            \
                const float inv = exp2f(-(float)(d & ~1) * ROPE_C);            \
                __bf16* dst = (region == 0) ? Qb : Kb;                         \
                _Pragma("unroll")                                              \
                for (int r = 0; r < 4; ++r) {                                  \
                    float v = (CV)[r];                                         \
                    const float vp = __shfl_xor(v, 1);                         \
                    const float ang = (float)tokpos[(t0 + r) & (SEQ - 1)] * inv;\
                    const float cth = cosf(ang), sth = sinf(ang);              \
                    v = (d & 1) ? (vp * sth + v * cth) : (v * cth - vp * sth); \
                    dst[(size_t)(t0 + r) * D_MODEL + col] = (__bf16)v;         \
                }                                                              \
            }                                                                  \
        }                                                                      \
    } while (0)

    EPI(0, 0, c00); EPI(0, 1, c01); EPI(0, 2, c02); EPI(0, 3, c03);
    EPI(1, 0, c10); EPI(1, 1, c11); EPI(1, 2, c12); EPI(1, 3, c13);
    EPI(2, 0, c20); EPI(2, 1, c21); EPI(2, 2, c22); EPI(2, 3, c23);
    EPI(3, 0, c30); EPI(3, 1, c31); EPI(3, 2, c32); EPI(3, 3, c33);
#undef EPI
}

// ---------------------------------------------------------------------------
// Causal flash attention v4 — 64 keys/iteration (transposed S^T scheme kept).
// r10 evidence: latency-bound (VALUBusy fell 28->19% with ~no time change);
// all waves resident. Fix: amortize the per-iter chain (softmax + LDS P
// round-trip) over 2x MFMA work: 8 score + 8 PV MFMAs per iter, half the
// iterations. exp folded to native exp2 (max tracked pre-scaled by
// C2 = 0.125*log2(e)). Exactly ONE masked tail step per tile
// (kt = 64*floor((q0+1)/64): kt <= q0 and q0+15 < kt+64 for q0 = 16t).
// P rows padded to 72 elems: 8-B aligned writes, 16-B aligned reads, <=2-way
// banks. Mirrored tile balance kept (pairs (t, 127-t): constant block work).
// O aliases Q in-place (each wave reads only its own rows first).
// ---------------------------------------------------------------------------
__global__ __launch_bounds__(256, 3) void attn_fused(
    const __bf16* Q, const __bf16* __restrict__ K,
    const __bf16* __restrict__ Vt, __bf16* O)
{
    const int tid  = threadIdx.x;
    const int wave = tid >> 6, lane = tid & 63;
    const int quad = lane >> 4, l16 = lane & 15;
    const int tsel = (wave < 2) ? (blockIdx.x * 2 + wave)
                                : (127 - (blockIdx.x * 2 + (wave - 2)));
    const int q0 = tsel * 16;
    const int bh = blockIdx.y;
    const size_t base  = (size_t)(bh >> 4) * SEQ * D_MODEL + (size_t)(bh & 15) * HEAD_DIM;
    const size_t vbase = (size_t)bh * HEAD_DIM * SEQ;
    const __bf16* kbase = K + base;

    __shared__ __bf16 P[4][16][72];   // per-wave; [query l16][key 0..63]

    const __bf16* qrow = Q + base + (size_t)(q0 + l16) * D_MODEL + quad * 8;
    const bf16x8 qf0 = *(const bf16x8*)(qrow);
    const bf16x8 qf1 = *(const bf16x8*)(qrow + 32);

    constexpr float C2 = 0.18033688011112042f;   // 0.125 * log2(e)
    float mm = -__builtin_inff(), l_i = 0.f;     // mm tracked in C2 units
    floatx4 o0 = {}, o1 = {}, o2 = {}, o3 = {};
    const int qg = q0 + l16;
    const int kt = ((q0 + 1) / 64) * 64;         // single masked tail block

#define ATTN_STEP(K0, MASKED)                                                  \
    do {                                                                       \
        const __bf16* kr = kbase + (size_t)((K0) + l16) * D_MODEL + quad * 8;  \
        const bf16x8 kb00 = *(const bf16x8*)(kr);                              \
        const bf16x8 kb01 = *(const bf16x8*)(kr + 32);                         \
        const bf16x8 kb10 = *(const bf16x8*)(kr + 16 * D_MODEL);               \
        const bf16x8 kb11 = *(const bf16x8*)(kr + 16 * D_MODEL + 32);          \
        const bf16x8 kb20 = *(const bf16x8*)(kr + 32 * D_MODEL);               \
        const bf16x8 kb21 = *(const bf16x8*)(kr + 32 * D_MODEL + 32);          \
        const bf16x8 kb30 = *(const bf16x8*)(kr + 48 * D_MODEL);               \
        const bf16x8 kb31 = *(const bf16x8*)(kr + 48 * D_MODEL + 32);          \
        const __bf16* vp = Vt + vbase + (size_t)l16 * SEQ + (K0) + quad * 8;   \
        const bf16x8 va00 = *(const bf16x8*)(vp);                              \
        const bf16x8 va01 = *(const bf16x8*)(vp + 32);                         \
        const bf16x8 va10 = *(const bf16x8*)(vp + 16 * SEQ);                   \
        const bf16x8 va11 = *(const bf16x8*)(vp + 16 * SEQ + 32);              \
        const bf16x8 va20 = *(const bf16x8*)(vp + 32 * SEQ);                   \
        const bf16x8 va21 = *(const bf16x8*)(vp + 32 * SEQ + 32);              \
        const bf16x8 va30 = *(const bf16x8*)(vp + 48 * SEQ);                   \
        const bf16x8 va31 = *(const bf16x8*)(vp + 48 * SEQ + 32);              \
        floatx4 s0 = {}, s1 = {}, s2 = {}, s3 = {};                            \
        s0 = MFMA16(kb00, qf0, s0); s0 = MFMA16(kb01, qf1, s0);                \
        s1 = MFMA16(kb10, qf0, s1); s1 = MFMA16(kb11, qf1, s1);                \
        s2 = MFMA16(kb20, qf0, s2); s2 = MFMA16(kb21, qf1, s2);                \
        s3 = MFMA16(kb30, qf0, s3); s3 = MFMA16(kb31, qf1, s3);                \
        if (MASKED) {                                                          \
            _Pragma("unroll")                                                  \
            for (int r = 0; r < 4; ++r) {                                      \
                const int kb = (K0) + quad * 4 + r;                            \
                if (kb      > qg) s0[r] = -__builtin_inff();                   \
                if (kb + 16 > qg) s1[r] = -__builtin_inff();                   \
                if (kb + 32 > qg) s2[r] = -__builtin_inff();                   \
                if (kb + 48 > qg) s3[r] = -__builtin_inff();                   \
            }                                                                  \
        }                                                                      \
        float mx = fmaxf(fmaxf(fmaxf(s0[0], s0[1]), fmaxf(s0[2], s0[3])),      \
                         fmaxf(fmaxf(s1[0], s1[1]), fmaxf(s1[2], s1[3])));     \
        mx = fmaxf(mx, fmaxf(fmaxf(fmaxf(s2[0], s2[1]), fmaxf(s2[2], s2[3])),  \
                             fmaxf(fmaxf(s3[0], s3[1]), fmaxf(s3[2], s3[3]))));\
        mx = fmaxf(mx, __shfl_xor(mx, 16));                                    \
        mx = fmaxf(mx, __shfl_xor(mx, 32));                                    \
        const float mmn  = fmaxf(mm, mx * C2);                                 \
        const float alpha = exp2f(mm - mmn);                                   \
        float rs = 0.f;                                                        \
        _Pragma("unroll")                                                      \
        for (int r = 0; r < 4; ++r) {                                          \
            s0[r] = exp2f(s0[r] * C2 - mmn);                                   \
            s1[r] = exp2f(s1[r] * C2 - mmn);                                   \
            s2[r] = exp2f(s2[r] * C2 - mmn);                                   \
            s3[r] = exp2f(s3[r] * C2 - mmn);                                   \
            rs += s0[r] + s1[r] + s2[r] + s3[r];                               \
        }                                                                      \
        rs += __shfl_xor(rs, 16);                                              \
        rs += __shfl_xor(rs, 32);                                              \
        l_i = l_i * alpha + rs;                                                \
        mm = mmn;                                                              \
        o0 *= alpha; o1 *= alpha; o2 *= alpha; o3 *= alpha;                    \
        bf16x4 pw0, pw1, pw2, pw3;                                             \
        _Pragma("unroll")                                                      \
        for (int r = 0; r < 4; ++r) {                                          \
            pw0[r] = (__bf16)s0[r]; pw1[r] = (__bf16)s1[r];                    \
            pw2[r] = (__bf16)s2[r]; pw3[r] = (__bf16)s3[r];                    \
        }                                                                      \
        *(bf16x4*)&P[wave][l16][quad * 4]      = pw0;                          \
        *(bf16x4*)&P[wave][l16][16 + quad * 4] = pw1;                          \
        *(bf16x4*)&P[wave][l16][32 + quad * 4] = pw2;                          \
        *(bf16x4*)&P[wave][l16][48 + quad * 4] = pw3;                          \
        const bf16x8 pp0 = *(const bf16x8*)&P[wave][l16][quad * 8];            \
        const bf16x8 pp1 = *(const bf16x8*)&P[wave][l16][32 + quad * 8];       \
        o0 = MFMA16(va00, pp0, o0); o0 = MFMA16(va01, pp1, o0);                \
        o1 = MFMA16(va10, pp0, o1); o1 = MFMA16(va11, pp1, o1);                \
        o2 = MFMA16(va20, pp0, o2); o2 = MFMA16(va21, pp1, o2);                \
        o3 = MFMA16(va30, pp0, o3); o3 = MFMA16(va31, pp1, o3);                \
    } while (0)

    for (int k0 = 0; k0 < kt; k0 += 64)
        ATTN_STEP(k0, false);    // unmasked body
    ATTN_STEP(kt, true);         // single masked tail
#undef ATTN_STEP

    // ---- epilogue: O[token q0+l16][dim g*16+quad*4+r], packed bf16x4 ----
    const float rl = 1.0f / l_i;
    __bf16* orow = O + base + (size_t)(q0 + l16) * D_MODEL + quad * 4;
    bf16x4 w0, w1, w2, w3;
#pragma unroll
    for (int r = 0; r < 4; ++r) {
        w0[r] = (__bf16)(o0[r] * rl);
        w1[r] = (__bf16)(o1[r] * rl);
        w2[r] = (__bf16)(o2[r] * rl);
        w3[r] = (__bf16)(o3[r] * rl);
    }
    *(bf16x4*)(orow)      = w0;
    *(bf16x4*)(orow + 16) = w1;
    *(bf16x4*)(orow + 32) = w2;
    *(bf16x4*)(orow + 48) = w3;
}

// ---------------------------------------------------------------------------
// ws layout (24 MB): Qb 8 | Kb 8 | Vt 8. Attention output in-place over Qb.
// Inputs fp32 (converted in GEMM staging), output fp32.
// ---------------------------------------------------------------------------
extern "C" void kernel_launch(void* const* d_in, const int* in_sizes, int n_in,
                              void* d_out, int out_size, void* d_ws, size_t ws_size,
                              hipStream_t stream) {
    const float* x  = (const float*)d_in[0];
    const int* pos  = (const int*)d_in[1];
    const float* Wq = (const float*)d_in[2];
    const float* Wk = (const float*)d_in[3];
    const float* Wv = (const float*)d_in[4];
    const float* Wo = (const float*)d_in[5];
    float* out = (float*)d_out;

    const size_t xe = (size_t)M_TOK * D_MODEL;   // 4M elements
    __bf16* Qb = (__bf16*)d_ws;
    __bf16* Kb = Qb + xe;
    __bf16* Vt = Kb + xe;                        // [b*16+h][64][2048]

    // 1. fused QKV projection (+RoPE, V transposed), conversion in staging
    gemm_tiled<0><<<dim3(M_TOK / 128, 3072 / 128), 256, 0, stream>>>(
        x, Wq, Wk, Wv, Qb, Kb, Vt, nullptr, pos);

    // 2. causal flash attention (64 keys/iter), in-place over Qb
    attn_fused<<<dim3(SEQ / 64, 2 * N_HEADS), 256, 0, stream>>>(Qb, Kb, Vt, Qb);

    // 3. output projection -> fp32 d_out
    gemm_tiled<1><<<dim3(M_TOK / 128, D_MODEL / 128), 256, 0, stream>>>(
        Qb, Wo, nullptr, nullptr, nullptr, nullptr, nullptr, out, pos);
}

// Round 12
// 258.769 us; speedup vs baseline: 1.1818x; 1.1818x over previous
//
#include <hip/hip_runtime.h>

typedef __bf16 bf16x4 __attribute__((ext_vector_type(4)));
typedef __bf16 bf16x8 __attribute__((ext_vector_type(8)));
typedef float floatx4 __attribute__((ext_vector_type(4)));

#define MFMA16(a, b, c) __builtin_amdgcn_mfma_f32_16x16x32_bf16((a), (b), (c), 0, 0, 0)

constexpr int D_MODEL = 1024;
constexpr int SEQ = 2048;
constexpr int HEAD_DIM = 64;
constexpr int M_TOK = 2 * SEQ;   // 4096 tokens (B=2)
constexpr int N_HEADS = 16;
constexpr float ROPE_C = 0.20762050593048596f;   // log2(10000)/64

// ---------------------------------------------------------------------------
// Single-dispatch fp32 -> bf16 conversion (r10-proven; fusing conversion into
// GEMM staging regressed r11 by ~33 us: staged tiles are re-read 24-32x and
// fp32 doubles those bytes).
// ---------------------------------------------------------------------------
__global__ __launch_bounds__(256) void convert_all(
    const float* __restrict__ x,  const float* __restrict__ wq,
    const float* __restrict__ wk, const float* __restrict__ wv,
    const float* __restrict__ wo, __bf16* __restrict__ dst)
{
    const size_t i = ((size_t)blockIdx.x * 256 + threadIdx.x) * 8;   // < 8M
    const float* s;
    size_t off;
    if (i < 4194304) { s = x; off = i; }
    else {
        const int w = (int)((i - 4194304) >> 20);
        off = (i - 4194304) & 1048575;
        s = (w == 0) ? wq : (w == 1) ? wk : (w == 2) ? wv : wo;
    }
    const floatx4 lo = *(const floatx4*)(s + off);
    const floatx4 hi = *(const floatx4*)(s + off + 4);
    bf16x8 v;
    v[0] = (__bf16)lo[0]; v[1] = (__bf16)lo[1]; v[2] = (__bf16)lo[2]; v[3] = (__bf16)lo[3];
    v[4] = (__bf16)hi[0]; v[5] = (__bf16)hi[1]; v[6] = (__bf16)hi[2]; v[7] = (__bf16)hi[3];
    *(bf16x8*)(dst + i) = v;
}

// ---------------------------------------------------------------------------
// Tiled GEMM (exact r10 revert). 128x128 tile, 4 waves, BK=32, bf16 inputs,
// unpadded 64-B LDS rows, 16 named floatx4 accumulators (r8 spill fix).
// MODE 0: fused QKV epilogue (N=3072); MODE 1: fp32 out projection.
// ---------------------------------------------------------------------------
template<int MODE>
__global__ __launch_bounds__(256, 2) void gemm_tiled(
    const __bf16* __restrict__ A, const __bf16* __restrict__ B,
    __bf16* __restrict__ Qb, __bf16* __restrict__ Kb, __bf16* __restrict__ Vt,
    float* __restrict__ Cf, const int* __restrict__ tokpos)
{
    __shared__ __bf16 As[128 * 32];
    __shared__ __bf16 Bs[128 * 32];
    const int tid  = threadIdx.x;
    const int wave = tid >> 6, lane = tid & 63;
    const int quad = lane >> 4, l16 = lane & 15;
    const int m0 = blockIdx.x * 128, n0 = blockIdx.y * 128;
    const int wm = (wave >> 1) * 64, wn = (wave & 1) * 64;

    floatx4 c00 = {}, c01 = {}, c02 = {}, c03 = {};
    floatx4 c10 = {}, c11 = {}, c12 = {}, c13 = {};
    floatx4 c20 = {}, c21 = {}, c22 = {}, c23 = {};
    floatx4 c30 = {}, c31 = {}, c32 = {}, c33 = {};

    const int sm = tid >> 2;
    const int sk = (tid & 3) * 8;
    const __bf16* gA = A + (size_t)(m0 + sm) * D_MODEL + sk;
    const __bf16* gB = B + (size_t)(n0 + sm) * D_MODEL + sk;

    for (int k0 = 0; k0 < D_MODEL; k0 += 32) {
        __syncthreads();
        *(bf16x8*)&As[sm * 32 + sk]        = *(const bf16x8*)(gA + k0);
        *(bf16x8*)&As[(sm + 64) * 32 + sk] = *(const bf16x8*)(gA + (size_t)64 * D_MODEL + k0);
        *(bf16x8*)&Bs[sm * 32 + sk]        = *(const bf16x8*)(gB + k0);
        *(bf16x8*)&Bs[(sm + 64) * 32 + sk] = *(const bf16x8*)(gB + (size_t)64 * D_MODEL + k0);
        __syncthreads();

        const bf16x8 a0 = *(const bf16x8*)&As[(wm      + l16) * 32 + quad * 8];
        const bf16x8 a1 = *(const bf16x8*)&As[(wm + 16 + l16) * 32 + quad * 8];
        const bf16x8 a2 = *(const bf16x8*)&As[(wm + 32 + l16) * 32 + quad * 8];
        const bf16x8 a3 = *(const bf16x8*)&As[(wm + 48 + l16) * 32 + quad * 8];
        const bf16x8 b0 = *(const bf16x8*)&Bs[(wn      + l16) * 32 + quad * 8];
        const bf16x8 b1 = *(const bf16x8*)&Bs[(wn + 16 + l16) * 32 + quad * 8];
        const bf16x8 b2 = *(const bf16x8*)&Bs[(wn + 32 + l16) * 32 + quad * 8];
        const bf16x8 b3 = *(const bf16x8*)&Bs[(wn + 48 + l16) * 32 + quad * 8];

        c00 = MFMA16(a0, b0, c00); c01 = MFMA16(a0, b1, c01);
        c02 = MFMA16(a0, b2, c02); c03 = MFMA16(a0, b3, c03);
        c10 = MFMA16(a1, b0, c10); c11 = MFMA16(a1, b1, c11);
        c12 = MFMA16(a1, b2, c12); c13 = MFMA16(a1, b3, c13);
        c20 = MFMA16(a2, b0, c20); c21 = MFMA16(a2, b1, c21);
        c22 = MFMA16(a2, b2, c22); c23 = MFMA16(a2, b3, c23);
        c30 = MFMA16(a3, b0, c30); c31 = MFMA16(a3, b1, c31);
        c32 = MFMA16(a3, b2, c32); c33 = MFMA16(a3, b3, c33);
    }

#define EPI(I, J, CV) do {                                                     \
        const int n  = n0 + wn + (J) * 16 + l16;                               \
        const int t0 = m0 + wm + (I) * 16 + quad * 4;                          \
        if (MODE == 1) {                                                       \
            Cf[(size_t)(t0 + 0) * D_MODEL + n] = (CV)[0];                      \
            Cf[(size_t)(t0 + 1) * D_MODEL + n] = (CV)[1];                      \
            Cf[(size_t)(t0 + 2) * D_MODEL + n] = (CV)[2];                      \
            Cf[(size_t)(t0 + 3) * D_MODEL + n] = (CV)[3];                      \
        } else {                                                               \
            const int region = n >> 10, col = n & 1023;                        \
            if (region == 2) {                                                 \
                bf16x4 v;                                                      \
                v[0] = (__bf16)(CV)[0]; v[1] = (__bf16)(CV)[1];                \
                v[2] = (__bf16)(CV)[2]; v[3] = (__bf16)(CV)[3];                \
                const size_t vidx =                                            \
                    ((size_t)(t0 >> 11) * 1024 + col) * SEQ + (t0 & (SEQ - 1));\
                *(bf16x4*)(Vt + vidx) = v;                                     \
            } else {                                                           \
                const int d = col & (HEAD_DIM - 1);                            \
                const float inv = exp2f(-(float)(d & ~1) * ROPE_C);            \
                __bf16* dst = (region == 0) ? Qb : Kb;                         \
                _Pragma("unroll")                                              \
                for (int r = 0; r < 4; ++r) {                                  \
                    float v = (CV)[r];                                         \
                    const float vp = __shfl_xor(v, 1);                         \
                    const float ang = (float)tokpos[(t0 + r) & (SEQ - 1)] * inv;\
                    const float cth = cosf(ang), sth = sinf(ang);              \
                    v = (d & 1) ? (vp * sth + v * cth) : (v * cth - vp * sth); \
                    dst[(size_t)(t0 + r) * D_MODEL + col] = (__bf16)v;         \
                }                                                              \
            }                                                                  \
        }                                                                      \
    } while (0)

    EPI(0, 0, c00); EPI(0, 1, c01); EPI(0, 2, c02); EPI(0, 3, c03);
    EPI(1, 0, c10); EPI(1, 1, c11); EPI(1, 2, c12); EPI(1, 3, c13);
    EPI(2, 0, c20); EPI(2, 1, c21); EPI(2, 2, c22); EPI(2, 3, c23);
    EPI(3, 0, c30); EPI(3, 1, c31); EPI(3, 2, c32); EPI(3, 3, c33);
#undef EPI
}

// ---------------------------------------------------------------------------
// Causal flash attention v5 — block-cooperative LDS staging.
// r11 diagnosis: wave-private K/V loads are 16-way scattered (16 lanes at
// 2/4 KB stride per bf16x8 load -> 16 cache lines each, L1 set-thrashing),
// duplicated 4x across a block's waves. Fix: one block = one 64-query tile;
// per 64-key iter the block stages K[64x64] and V[64x64] into LDS with
// COALESCED 128-B row loads, then each wave computes its 16-query strip from
// LDS (b128 reads, 72-elem row pad -> <=2-way banks = free). Math identical
// to r11 (transposed S^T scheme, exp2, single masked tail at k0 == Q0).
// Longest-tile-first (T = 31-bx) for LPT drain. O aliases Q in-place.
// ---------------------------------------------------------------------------
__global__ __launch_bounds__(256, 4) void attn_fused(
    const __bf16* Q, const __bf16* __restrict__ K,
    const __bf16* __restrict__ Vt, __bf16* O)
{
    const int tid  = threadIdx.x;
    const int wave = tid >> 6, lane = tid & 63;
    const int quad = lane >> 4, l16 = lane & 15;
    const int T  = 31 - blockIdx.x;          // longest first
    const int Q0 = T * 64;
    const int bh = blockIdx.y;
    const size_t base  = (size_t)(bh >> 4) * SEQ * D_MODEL + (size_t)(bh & 15) * HEAD_DIM;
    const __bf16* kbase  = K + base;
    const __bf16* vtbase = Vt + (size_t)bh * HEAD_DIM * SEQ;

    __shared__ __bf16 Ks[64][72];    // [key r][dim d]
    __shared__ __bf16 Vs[64][72];    // [dim d][key c]
    __shared__ __bf16 P[4][16][72];  // per-wave [query l16][key 0..63]

    const int q0w = Q0 + wave * 16;
    const __bf16* qrow = Q + base + (size_t)(q0w + l16) * D_MODEL + quad * 8;
    const bf16x8 qf0 = *(const bf16x8*)(qrow);
    const bf16x8 qf1 = *(const bf16x8*)(qrow + 32);

    constexpr float C2 = 0.18033688011112042f;   // 0.125 * log2(e)
    float mm = -__builtin_inff(), l_i = 0.f;     // max tracked in C2 units
    floatx4 o0 = {}, o1 = {}, o2 = {}, o3 = {};  // O^T: dim dg*16+l16... (see epi)
    const int qg = q0w + l16;

    const int sr = tid >> 2;            // staging row 0..63
    const int sc = (tid & 3) * 16;      // staging col 0,16,32,48

    for (int k0 = 0; k0 <= Q0; k0 += 64) {
        __syncthreads();   // protect previous iteration's LDS reads
        {
            const __bf16* kgp = kbase + (size_t)(k0 + sr) * D_MODEL + sc;
            *(bf16x8*)&Ks[sr][sc]     = *(const bf16x8*)(kgp);
            *(bf16x8*)&Ks[sr][sc + 8] = *(const bf16x8*)(kgp + 8);
            const __bf16* vgp = vtbase + (size_t)sr * SEQ + k0 + sc;
            *(bf16x8*)&Vs[sr][sc]     = *(const bf16x8*)(vgp);
            *(bf16x8*)&Vs[sr][sc + 8] = *(const bf16x8*)(vgp + 8);
        }
        __syncthreads();

        // ---- scores: S^T[64 keys][16 queries], A = K rows from LDS ----
        floatx4 s0 = {}, s1 = {}, s2 = {}, s3 = {};
        s0 = MFMA16(*(const bf16x8*)&Ks[l16][quad * 8],      qf0, s0);
        s0 = MFMA16(*(const bf16x8*)&Ks[l16][32 + quad * 8], qf1, s0);
        s1 = MFMA16(*(const bf16x8*)&Ks[16 + l16][quad * 8],      qf0, s1);
        s1 = MFMA16(*(const bf16x8*)&Ks[16 + l16][32 + quad * 8], qf1, s1);
        s2 = MFMA16(*(const bf16x8*)&Ks[32 + l16][quad * 8],      qf0, s2);
        s2 = MFMA16(*(const bf16x8*)&Ks[32 + l16][32 + quad * 8], qf1, s2);
        s3 = MFMA16(*(const bf16x8*)&Ks[48 + l16][quad * 8],      qf0, s3);
        s3 = MFMA16(*(const bf16x8*)&Ks[48 + l16][32 + quad * 8], qf1, s3);

        if (k0 == Q0) {   // single masked tail block
#pragma unroll
            for (int r = 0; r < 4; ++r) {
                const int kb = k0 + quad * 4 + r;
                if (kb      > qg) s0[r] = -__builtin_inff();
                if (kb + 16 > qg) s1[r] = -__builtin_inff();
                if (kb + 32 > qg) s2[r] = -__builtin_inff();
                if (kb + 48 > qg) s3[r] = -__builtin_inff();
            }
        }

        // ---- online softmax over 64 keys (per-lane scalar state) ----
        float mx = fmaxf(fmaxf(fmaxf(s0[0], s0[1]), fmaxf(s0[2], s0[3])),
                         fmaxf(fmaxf(s1[0], s1[1]), fmaxf(s1[2], s1[3])));
        mx = fmaxf(mx, fmaxf(fmaxf(fmaxf(s2[0], s2[1]), fmaxf(s2[2], s2[3])),
                             fmaxf(fmaxf(s3[0], s3[1]), fmaxf(s3[2], s3[3]))));
        mx = fmaxf(mx, __shfl_xor(mx, 16));
        mx = fmaxf(mx, __shfl_xor(mx, 32));
        const float mmn  = fmaxf(mm, mx * C2);
        const float alpha = exp2f(mm - mmn);
        float rs = 0.f;
#pragma unroll
        for (int r = 0; r < 4; ++r) {
            s0[r] = exp2f(s0[r] * C2 - mmn);
            s1[r] = exp2f(s1[r] * C2 - mmn);
            s2[r] = exp2f(s2[r] * C2 - mmn);
            s3[r] = exp2f(s3[r] * C2 - mmn);
            rs += s0[r] + s1[r] + s2[r] + s3[r];
        }
        rs += __shfl_xor(rs, 16);
        rs += __shfl_xor(rs, 32);
        l_i = l_i * alpha + rs;
        mm = mmn;
        o0 *= alpha; o1 *= alpha; o2 *= alpha; o3 *= alpha;

        // ---- P: C-layout -> per-wave LDS -> A(B)-layout ----
        bf16x4 pw0, pw1, pw2, pw3;
#pragma unroll
        for (int r = 0; r < 4; ++r) {
            pw0[r] = (__bf16)s0[r]; pw1[r] = (__bf16)s1[r];
            pw2[r] = (__bf16)s2[r]; pw3[r] = (__bf16)s3[r];
        }
        *(bf16x4*)&P[wave][l16][quad * 4]      = pw0;
        *(bf16x4*)&P[wave][l16][16 + quad * 4] = pw1;
        *(bf16x4*)&P[wave][l16][32 + quad * 4] = pw2;
        *(bf16x4*)&P[wave][l16][48 + quad * 4] = pw3;
        const bf16x8 pp0 = *(const bf16x8*)&P[wave][l16][quad * 8];
        const bf16x8 pp1 = *(const bf16x8*)&P[wave][l16][32 + quad * 8];

        // ---- PV: O^T[dim][16q], A = V rows from LDS ----
        o0 = MFMA16(*(const bf16x8*)&Vs[l16][quad * 8],      pp0, o0);
        o0 = MFMA16(*(const bf16x8*)&Vs[l16][32 + quad * 8], pp1, o0);
        o1 = MFMA16(*(const bf16x8*)&Vs[16 + l16][quad * 8],      pp0, o1);
        o1 = MFMA16(*(const bf16x8*)&Vs[16 + l16][32 + quad * 8], pp1, o1);
        o2 = MFMA16(*(const bf16x8*)&Vs[32 + l16][quad * 8],      pp0, o2);
        o2 = MFMA16(*(const bf16x8*)&Vs[32 + l16][32 + quad * 8], pp1, o2);
        o3 = MFMA16(*(const bf16x8*)&Vs[48 + l16][quad * 8],      pp0, o3);
        o3 = MFMA16(*(const bf16x8*)&Vs[48 + l16][32 + quad * 8], pp1, o3);
    }

    // ---- epilogue: O[token q0w+l16][dim dg*16+quad*4+r], packed bf16x4 ----
    const float rl = 1.0f / l_i;
    __bf16* orow = O + base + (size_t)(q0w + l16) * D_MODEL + quad * 4;
    bf16x4 w0, w1, w2, w3;
#pragma unroll
    for (int r = 0; r < 4; ++r) {
        w0[r] = (__bf16)(o0[r] * rl);
        w1[r] = (__bf16)(o1[r] * rl);
        w2[r] = (__bf16)(o2[r] * rl);
        w3[r] = (__bf16)(o3[r] * rl);
    }
    *(bf16x4*)(orow)      = w0;
    *(bf16x4*)(orow + 16) = w1;
    *(bf16x4*)(orow + 32) = w2;
    *(bf16x4*)(orow + 48) = w3;
}

// ---------------------------------------------------------------------------
// ws layout (40 MB): Xb 8 | Wb (Wq,Wk,Wv,Wo cat) 8 | Qb 8 | Kb 8 | Vt 8.
// Attention output in-place over Qb. Inputs fp32, output fp32.
// ---------------------------------------------------------------------------
extern "C" void kernel_launch(void* const* d_in, const int* in_sizes, int n_in,
                              void* d_out, int out_size, void* d_ws, size_t ws_size,
                              hipStream_t stream) {
    const int* pos = (const int*)d_in[1];
    float* out = (float*)d_out;

    const size_t xe = (size_t)M_TOK * D_MODEL;      // 4M elements
    const size_t we = (size_t)D_MODEL * D_MODEL;    // 1M elements
    __bf16* Xb = (__bf16*)d_ws;
    __bf16* Wb = Xb + xe;          // [Wq | Wk | Wv | Wo]
    __bf16* Qb = Wb + 4 * we;
    __bf16* Kb = Qb + xe;
    __bf16* Vt = Kb + xe;          // [b*16+h][64][2048] transposed V

    convert_all<<<4096, 256, 0, stream>>>(
        (const float*)d_in[0], (const float*)d_in[2], (const float*)d_in[3],
        (const float*)d_in[4], (const float*)d_in[5], Xb);

    gemm_tiled<0><<<dim3(M_TOK / 128, 3072 / 128), 256, 0, stream>>>(
        Xb, Wb, Qb, Kb, Vt, nullptr, pos);

    // 32 q-tiles (64 queries each) x 32 bh
    attn_fused<<<dim3(SEQ / 64, 2 * N_HEADS), 256, 0, stream>>>(Qb, Kb, Vt, Qb);

    gemm_tiled<1><<<dim3(M_TOK / 128, D_MODEL / 128), 256, 0, stream>>>(
        Qb, Wb + 3 * we, nullptr, nullptr, nullptr, out, pos);
}

// Round 13
// 223.171 us; speedup vs baseline: 1.3703x; 1.1595x over previous
//
#include <hip/hip_runtime.h>

typedef __bf16 bf16x4 __attribute__((ext_vector_type(4)));
typedef __bf16 bf16x8 __attribute__((ext_vector_type(8)));
typedef float floatx4 __attribute__((ext_vector_type(4)));

#define MFMA16(a, b, c) __builtin_amdgcn_mfma_f32_16x16x32_bf16((a), (b), (c), 0, 0, 0)

constexpr int D_MODEL = 1024;
constexpr int SEQ = 2048;
constexpr int HEAD_DIM = 64;
constexpr int M_TOK = 2 * SEQ;   // 4096 tokens (B=2)
constexpr int N_HEADS = 16;
constexpr float ROPE_C = 0.20762050593048596f;   // log2(10000)/64

// ---------------------------------------------------------------------------
// Single-dispatch fp32 -> bf16 conversion (r10-proven).
// ---------------------------------------------------------------------------
__global__ __launch_bounds__(256) void convert_all(
    const float* __restrict__ x,  const float* __restrict__ wq,
    const float* __restrict__ wk, const float* __restrict__ wv,
    const float* __restrict__ wo, __bf16* __restrict__ dst)
{
    const size_t i = ((size_t)blockIdx.x * 256 + threadIdx.x) * 8;   // < 8M
    const float* s;
    size_t off;
    if (i < 4194304) { s = x; off = i; }
    else {
        const int w = (int)((i - 4194304) >> 20);
        off = (i - 4194304) & 1048575;
        s = (w == 0) ? wq : (w == 1) ? wk : (w == 2) ? wv : wo;
    }
    const floatx4 lo = *(const floatx4*)(s + off);
    const floatx4 hi = *(const floatx4*)(s + off + 4);
    bf16x8 v;
    v[0] = (__bf16)lo[0]; v[1] = (__bf16)lo[1]; v[2] = (__bf16)lo[2]; v[3] = (__bf16)lo[3];
    v[4] = (__bf16)hi[0]; v[5] = (__bf16)hi[1]; v[6] = (__bf16)hi[2]; v[7] = (__bf16)hi[3];
    *(bf16x8*)(dst + i) = v;
}

// ---------------------------------------------------------------------------
// Tiled GEMM (unchanged from r12). 128x128 tile, 4 waves, BK=32, bf16 in,
// unpadded 64-B LDS rows, 16 named floatx4 accumulators (r8 spill fix).
// MODE 0: fused QKV epilogue (N=3072); MODE 1: fp32 out projection.
// ---------------------------------------------------------------------------
template<int MODE>
__global__ __launch_bounds__(256, 2) void gemm_tiled(
    const __bf16* __restrict__ A, const __bf16* __restrict__ B,
    __bf16* __restrict__ Qb, __bf16* __restrict__ Kb, __bf16* __restrict__ Vt,
    float* __restrict__ Cf, const int* __restrict__ tokpos)
{
    __shared__ __bf16 As[128 * 32];
    __shared__ __bf16 Bs[128 * 32];
    const int tid  = threadIdx.x;
    const int wave = tid >> 6, lane = tid & 63;
    const int quad = lane >> 4, l16 = lane & 15;
    const int m0 = blockIdx.x * 128, n0 = blockIdx.y * 128;
    const int wm = (wave >> 1) * 64, wn = (wave & 1) * 64;

    floatx4 c00 = {}, c01 = {}, c02 = {}, c03 = {};
    floatx4 c10 = {}, c11 = {}, c12 = {}, c13 = {};
    floatx4 c20 = {}, c21 = {}, c22 = {}, c23 = {};
    floatx4 c30 = {}, c31 = {}, c32 = {}, c33 = {};

    const int sm = tid >> 2;
    const int sk = (tid & 3) * 8;
    const __bf16* gA = A + (size_t)(m0 + sm) * D_MODEL + sk;
    const __bf16* gB = B + (size_t)(n0 + sm) * D_MODEL + sk;

    for (int k0 = 0; k0 < D_MODEL; k0 += 32) {
        __syncthreads();
        *(bf16x8*)&As[sm * 32 + sk]        = *(const bf16x8*)(gA + k0);
        *(bf16x8*)&As[(sm + 64) * 32 + sk] = *(const bf16x8*)(gA + (size_t)64 * D_MODEL + k0);
        *(bf16x8*)&Bs[sm * 32 + sk]        = *(const bf16x8*)(gB + k0);
        *(bf16x8*)&Bs[(sm + 64) * 32 + sk] = *(const bf16x8*)(gB + (size_t)64 * D_MODEL + k0);
        __syncthreads();

        const bf16x8 a0 = *(const bf16x8*)&As[(wm      + l16) * 32 + quad * 8];
        const bf16x8 a1 = *(const bf16x8*)&As[(wm + 16 + l16) * 32 + quad * 8];
        const bf16x8 a2 = *(const bf16x8*)&As[(wm + 32 + l16) * 32 + quad * 8];
        const bf16x8 a3 = *(const bf16x8*)&As[(wm + 48 + l16) * 32 + quad * 8];
        const bf16x8 b0 = *(const bf16x8*)&Bs[(wn      + l16) * 32 + quad * 8];
        const bf16x8 b1 = *(const bf16x8*)&Bs[(wn + 16 + l16) * 32 + quad * 8];
        const bf16x8 b2 = *(const bf16x8*)&Bs[(wn + 32 + l16) * 32 + quad * 8];
        const bf16x8 b3 = *(const bf16x8*)&Bs[(wn + 48 + l16) * 32 + quad * 8];

        c00 = MFMA16(a0, b0, c00); c01 = MFMA16(a0, b1, c01);
        c02 = MFMA16(a0, b2, c02); c03 = MFMA16(a0, b3, c03);
        c10 = MFMA16(a1, b0, c10); c11 = MFMA16(a1, b1, c11);
        c12 = MFMA16(a1, b2, c12); c13 = MFMA16(a1, b3, c13);
        c20 = MFMA16(a2, b0, c20); c21 = MFMA16(a2, b1, c21);
        c22 = MFMA16(a2, b2, c22); c23 = MFMA16(a2, b3, c23);
        c30 = MFMA16(a3, b0, c30); c31 = MFMA16(a3, b1, c31);
        c32 = MFMA16(a3, b2, c32); c33 = MFMA16(a3, b3, c33);
    }

#define EPI(I, J, CV) do {                                                     \
        const int n  = n0 + wn + (J) * 16 + l16;                               \
        const int t0 = m0 + wm + (I) * 16 + quad * 4;                          \
        if (MODE == 1) {                                                       \
            Cf[(size_t)(t0 + 0) * D_MODEL + n] = (CV)[0];                      \
            Cf[(size_t)(t0 + 1) * D_MODEL + n] = (CV)[1];                      \
            Cf[(size_t)(t0 + 2) * D_MODEL + n] = (CV)[2];                      \
            Cf[(size_t)(t0 + 3) * D_MODEL + n] = (CV)[3];                      \
        } else {                                                               \
            const int region = n >> 10, col = n & 1023;                        \
            if (region == 2) {                                                 \
                bf16x4 v;                                                      \
                v[0] = (__bf16)(CV)[0]; v[1] = (__bf16)(CV)[1];                \
                v[2] = (__bf16)(CV)[2]; v[3] = (__bf16)(CV)[3];                \
                const size_t vidx =                                            \
                    ((size_t)(t0 >> 11) * 1024 + col) * SEQ + (t0 & (SEQ - 1));\
                *(bf16x4*)(Vt + vidx) = v;                                     \
            } else {                                                           \
                const int d = col & (HEAD_DIM - 1);                            \
                const float inv = exp2f(-(float)(d & ~1) * ROPE_C);            \
                __bf16* dst = (region == 0) ? Qb : Kb;                         \
                _Pragma("unroll")                                              \
                for (int r = 0; r < 4; ++r) {                                  \
                    float v = (CV)[r];                                         \
                    const float vp = __shfl_xor(v, 1);                         \
                    const float ang = (float)tokpos[(t0 + r) & (SEQ - 1)] * inv;\
                    const float cth = cosf(ang), sth = sinf(ang);              \
                    v = (d & 1) ? (vp * sth + v * cth) : (v * cth - vp * sth); \
                    dst[(size_t)(t0 + r) * D_MODEL + col] = (__bf16)v;         \
                }                                                              \
            }                                                                  \
        }                                                                      \
    } while (0)

    EPI(0, 0, c00); EPI(0, 1, c01); EPI(0, 2, c02); EPI(0, 3, c03);
    EPI(1, 0, c10); EPI(1, 1, c11); EPI(1, 2, c12); EPI(1, 3, c13);
    EPI(2, 0, c20); EPI(2, 1, c21); EPI(2, 2, c22); EPI(2, 3, c23);
    EPI(3, 0, c30); EPI(3, 1, c31); EPI(3, 2, c32); EPI(3, 3, c33);
#undef EPI
}

// ---------------------------------------------------------------------------
// Causal flash attention v6 — r12 cooperative-staging kernel + PAIRED tiles.
// r12 evidence: OccupancyPercent 18% (time-avg) — with grid (32,32) every
// CU got 4 blocks of the SAME bx (256 = 0 mod 32), work = 32-bx iters each:
// worst CU 128 iters vs best 4 (2x drain). Fix: block bx processes tile
// T=bx THEN tile T=31-bx sequentially — per-block work = 33 staged iters,
// exactly constant, balanced under ANY CU assignment. Grid (16,32), 2/CU.
// Per-tile math/staging identical to r12.
// ---------------------------------------------------------------------------
__global__ __launch_bounds__(256, 4) void attn_fused(
    const __bf16* Q, const __bf16* __restrict__ K,
    const __bf16* __restrict__ Vt, __bf16* O)
{
    const int tid  = threadIdx.x;
    const int wave = tid >> 6, lane = tid & 63;
    const int quad = lane >> 4, l16 = lane & 15;
    const int bh = blockIdx.y;
    const size_t base  = (size_t)(bh >> 4) * SEQ * D_MODEL + (size_t)(bh & 15) * HEAD_DIM;
    const __bf16* kbase  = K + base;
    const __bf16* vtbase = Vt + (size_t)bh * HEAD_DIM * SEQ;

    __shared__ __bf16 Ks[64][72];    // [key][dim]
    __shared__ __bf16 Vs[64][72];    // [dim][key]
    __shared__ __bf16 P[4][16][72];  // per-wave [query l16][key 0..63]

    constexpr float C2 = 0.18033688011112042f;   // 0.125 * log2(e)
    const int sr = tid >> 2;            // staging row 0..63
    const int sc = (tid & 3) * 16;      // staging col 0,16,32,48

    auto process_tile = [&](int T) {
        const int Q0  = T * 64;
        const int q0w = Q0 + wave * 16;
        const int qg  = q0w + l16;

        const __bf16* qrow = Q + base + (size_t)(q0w + l16) * D_MODEL + quad * 8;
        const bf16x8 qf0 = *(const bf16x8*)(qrow);
        const bf16x8 qf1 = *(const bf16x8*)(qrow + 32);

        float mm = -__builtin_inff(), l_i = 0.f;
        floatx4 o0 = {}, o1 = {}, o2 = {}, o3 = {};

        for (int k0 = 0; k0 <= Q0; k0 += 64) {
            __syncthreads();   // protect previous iteration/phase LDS reads
            {
                const __bf16* kgp = kbase + (size_t)(k0 + sr) * D_MODEL + sc;
                *(bf16x8*)&Ks[sr][sc]     = *(const bf16x8*)(kgp);
                *(bf16x8*)&Ks[sr][sc + 8] = *(const bf16x8*)(kgp + 8);
                const __bf16* vgp = vtbase + (size_t)sr * SEQ + k0 + sc;
                *(bf16x8*)&Vs[sr][sc]     = *(const bf16x8*)(vgp);
                *(bf16x8*)&Vs[sr][sc + 8] = *(const bf16x8*)(vgp + 8);
            }
            __syncthreads();

            // ---- scores: S^T[64 keys][16 queries], A = K rows from LDS ----
            floatx4 s0 = {}, s1 = {}, s2 = {}, s3 = {};
            s0 = MFMA16(*(const bf16x8*)&Ks[l16][quad * 8],      qf0, s0);
            s0 = MFMA16(*(const bf16x8*)&Ks[l16][32 + quad * 8], qf1, s0);
            s1 = MFMA16(*(const bf16x8*)&Ks[16 + l16][quad * 8],      qf0, s1);
            s1 = MFMA16(*(const bf16x8*)&Ks[16 + l16][32 + quad * 8], qf1, s1);
            s2 = MFMA16(*(const bf16x8*)&Ks[32 + l16][quad * 8],      qf0, s2);
            s2 = MFMA16(*(const bf16x8*)&Ks[32 + l16][32 + quad * 8], qf1, s2);
            s3 = MFMA16(*(const bf16x8*)&Ks[48 + l16][quad * 8],      qf0, s3);
            s3 = MFMA16(*(const bf16x8*)&Ks[48 + l16][32 + quad * 8], qf1, s3);

            if (k0 == Q0) {   // single masked tail block
#pragma unroll
                for (int r = 0; r < 4; ++r) {
                    const int kb = k0 + quad * 4 + r;
                    if (kb      > qg) s0[r] = -__builtin_inff();
                    if (kb + 16 > qg) s1[r] = -__builtin_inff();
                    if (kb + 32 > qg) s2[r] = -__builtin_inff();
                    if (kb + 48 > qg) s3[r] = -__builtin_inff();
                }
            }

            // ---- online softmax over 64 keys (per-lane scalar state) ----
            float mx = fmaxf(fmaxf(fmaxf(s0[0], s0[1]), fmaxf(s0[2], s0[3])),
                             fmaxf(fmaxf(s1[0], s1[1]), fmaxf(s1[2], s1[3])));
            mx = fmaxf(mx, fmaxf(fmaxf(fmaxf(s2[0], s2[1]), fmaxf(s2[2], s2[3])),
                                 fmaxf(fmaxf(s3[0], s3[1]), fmaxf(s3[2], s3[3]))));
            mx = fmaxf(mx, __shfl_xor(mx, 16));
            mx = fmaxf(mx, __shfl_xor(mx, 32));
            const float mmn  = fmaxf(mm, mx * C2);
            const float alpha = exp2f(mm - mmn);
            float rs = 0.f;
#pragma unroll
            for (int r = 0; r < 4; ++r) {
                s0[r] = exp2f(s0[r] * C2 - mmn);
                s1[r] = exp2f(s1[r] * C2 - mmn);
                s2[r] = exp2f(s2[r] * C2 - mmn);
                s3[r] = exp2f(s3[r] * C2 - mmn);
                rs += s0[r] + s1[r] + s2[r] + s3[r];
            }
            rs += __shfl_xor(rs, 16);
            rs += __shfl_xor(rs, 32);
            l_i = l_i * alpha + rs;
            mm = mmn;
            o0 *= alpha; o1 *= alpha; o2 *= alpha; o3 *= alpha;

            // ---- P: C-layout -> per-wave LDS -> A-layout ----
            bf16x4 pw0, pw1, pw2, pw3;
#pragma unroll
            for (int r = 0; r < 4; ++r) {
                pw0[r] = (__bf16)s0[r]; pw1[r] = (__bf16)s1[r];
                pw2[r] = (__bf16)s2[r]; pw3[r] = (__bf16)s3[r];
            }
            *(bf16x4*)&P[wave][l16][quad * 4]      = pw0;
            *(bf16x4*)&P[wave][l16][16 + quad * 4] = pw1;
            *(bf16x4*)&P[wave][l16][32 + quad * 4] = pw2;
            *(bf16x4*)&P[wave][l16][48 + quad * 4] = pw3;
            const bf16x8 pp0 = *(const bf16x8*)&P[wave][l16][quad * 8];
            const bf16x8 pp1 = *(const bf16x8*)&P[wave][l16][32 + quad * 8];

            // ---- PV: O^T[dim][16q], A = V rows from LDS ----
            o0 = MFMA16(*(const bf16x8*)&Vs[l16][quad * 8],      pp0, o0);
            o0 = MFMA16(*(const bf16x8*)&Vs[l16][32 + quad * 8], pp1, o0);
            o1 = MFMA16(*(const bf16x8*)&Vs[16 + l16][quad * 8],      pp0, o1);
            o1 = MFMA16(*(const bf16x8*)&Vs[16 + l16][32 + quad * 8], pp1, o1);
            o2 = MFMA16(*(const bf16x8*)&Vs[32 + l16][quad * 8],      pp0, o2);
            o2 = MFMA16(*(const bf16x8*)&Vs[32 + l16][32 + quad * 8], pp1, o2);
            o3 = MFMA16(*(const bf16x8*)&Vs[48 + l16][quad * 8],      pp0, o3);
            o3 = MFMA16(*(const bf16x8*)&Vs[48 + l16][32 + quad * 8], pp1, o3);
        }

        // ---- epilogue: O[token q0w+l16][dim quad*4+r + 16g], bf16x4 ----
        const float rl = 1.0f / l_i;
        __bf16* orow = O + base + (size_t)(q0w + l16) * D_MODEL + quad * 4;
        bf16x4 w0, w1, w2, w3;
#pragma unroll
        for (int r = 0; r < 4; ++r) {
            w0[r] = (__bf16)(o0[r] * rl);
            w1[r] = (__bf16)(o1[r] * rl);
            w2[r] = (__bf16)(o2[r] * rl);
            w3[r] = (__bf16)(o3[r] * rl);
        }
        *(bf16x4*)(orow)      = w0;
        *(bf16x4*)(orow + 16) = w1;
        *(bf16x4*)(orow + 32) = w2;
        *(bf16x4*)(orow + 48) = w3;
    };

    process_tile(blockIdx.x);          // short tile  (bx+1 staged iters)
    process_tile(31 - blockIdx.x);     // long tile   (32-bx staged iters)
}

// ---------------------------------------------------------------------------
// ws layout (40 MB): Xb 8 | Wb (Wq,Wk,Wv,Wo cat) 8 | Qb 8 | Kb 8 | Vt 8.
// Attention output in-place over Qb. Inputs fp32, output fp32.
// ---------------------------------------------------------------------------
extern "C" void kernel_launch(void* const* d_in, const int* in_sizes, int n_in,
                              void* d_out, int out_size, void* d_ws, size_t ws_size,
                              hipStream_t stream) {
    const int* pos = (const int*)d_in[1];
    float* out = (float*)d_out;

    const size_t xe = (size_t)M_TOK * D_MODEL;      // 4M elements
    const size_t we = (size_t)D_MODEL * D_MODEL;    // 1M elements
    __bf16* Xb = (__bf16*)d_ws;
    __bf16* Wb = Xb + xe;          // [Wq | Wk | Wv | Wo]
    __bf16* Qb = Wb + 4 * we;
    __bf16* Kb = Qb + xe;
    __bf16* Vt = Kb + xe;          // [b*16+h][64][2048] transposed V

    convert_all<<<4096, 256, 0, stream>>>(
        (const float*)d_in[0], (const float*)d_in[2], (const float*)d_in[3],
        (const float*)d_in[4], (const float*)d_in[5], Xb);

    gemm_tiled<0><<<dim3(M_TOK / 128, 3072 / 128), 256, 0, stream>>>(
        Xb, Wb, Qb, Kb, Vt, nullptr, pos);

    // paired mirrored tiles: 16 pair-blocks x 32 bh, constant 33 iters/block
    attn_fused<<<dim3(16, 2 * N_HEADS), 256, 0, stream>>>(Qb, Kb, Vt, Qb);

    gemm_tiled<1><<<dim3(M_TOK / 128, D_MODEL / 128), 256, 0, stream>>>(
        Qb, Wb + 3 * we, nullptr, nullptr, nullptr, out, pos);
}